// Round 8
// baseline (362.350 us; speedup 1.0000x reference)
//
#include <hip/hip_runtime.h>
#include <hip/hip_bf16.h>
#include <math.h>

#define DF 128
#define NC 40
#define PC 20            // classes per plane; 40 B plane rows; 4 MB/plane = one XCD L2
#define PROWB 40         // plane row bytes
#define RB 8             // bucket = node >> 8 (256 nodes/bucket)
#define RSZ 256
#define CHUNK 4096       // edges per binning block
#define CAP 12288        // slab capacity per bucket

typedef float f32x4 __attribute__((ext_vector_type(4)));

__device__ __forceinline__ float bf2f(unsigned short h) {
  unsigned int u = ((unsigned int)h) << 16;
  union { unsigned int u; float f; } c; c.u = u; return c.f;
}
__device__ __forceinline__ unsigned short f2bf(float x) {  // round-to-nearest-even
  union { float f; unsigned int u; } c; c.f = x;
  unsigned int u = c.u;
  return (unsigned short)((u + 0x7fffu + ((u >> 16) & 1u)) >> 16);
}
__device__ __forceinline__ float blo(unsigned int u) {
  union { unsigned int u; float f; } c; c.u = u << 16; return c.f;
}
__device__ __forceinline__ float bhi(unsigned int u) {
  union { unsigned int u; float f; } c; c.u = u & 0xffff0000u; return c.f;
}

// ---------- pass B: bin edges into per-bucket slab, count totals ----------
__global__ __launch_bounds__(512) void k_binB(
    const int* __restrict__ row, const int* __restrict__ col,
    int* __restrict__ cnt, unsigned int* __restrict__ slab, int E, int NB) {
  __shared__ int colS[CHUNK];   // 16 KB
  __shared__ int hist[512];
  __shared__ int cursor[512];
  int t = threadIdx.x;
  if (t < NB) hist[t] = 0;
  int s = blockIdx.x * CHUNK, e = min(E, s + CHUNK), n = e - s;
  for (int i = t; i < n; i += 512) colS[i] = col[s + i];
  __syncthreads();
  for (int i = t; i < n; i += 512) atomicAdd(&hist[colS[i] >> RB], 1);
  __syncthreads();
  if (t < NB) cursor[t] = hist[t] ? atomicAdd(&cnt[t], hist[t]) : 0;
  __syncthreads();
  for (int i = t; i < n; i += 512) {
    int c = colS[i];
    int b = c >> RB;
    int p = atomicAdd(&cursor[b], 1);
    slab[(size_t)b * CAP + p] = ((unsigned int)row[s + i] << RB) | (unsigned int)(c & (RSZ - 1));
  }
}

// ---------- pass C: per-bucket CSR finalize + dinv (bucket base inline) ----------
// eidx entries are PRE-SCALED to plane-row byte offsets (r * 40).
__global__ __launch_bounds__(512) void k_binC(
    const unsigned int* __restrict__ slab, const int* __restrict__ cnt,
    int* __restrict__ off, int* __restrict__ eidx, float* __restrict__ dinv,
    int N, int NB, int E) {
  __shared__ int redS[512];
  __shared__ int hist[RSZ];
  __shared__ int sc[RSZ];
  __shared__ int cur[RSZ];
  int b = blockIdx.x;
  int t = threadIdx.x;
  redS[t] = (t < NB && t < b) ? cnt[t] : 0;
  if (t < RSZ) hist[t] = 0;
  __syncthreads();
  for (int o = 256; o > 0; o >>= 1) {
    if (t < o) redS[t] += redS[t + o];
    __syncthreads();
  }
  int cb = redS[0];
  int cnt_b = cnt[b];
  if (b == 0 && t == 0) off[N] = E;
  const unsigned int* src = slab + (size_t)b * CAP;
  for (int i = t; i < cnt_b; i += 512) atomicAdd(&hist[src[i] & (RSZ - 1)], 1);
  __syncthreads();
  int v = (t < RSZ) ? hist[t] : 0;
  if (t < RSZ) sc[t] = v;
  __syncthreads();
  for (int o = 1; o < RSZ; o <<= 1) {
    int u = (t < RSZ && t >= o) ? sc[t - o] : 0;
    __syncthreads();
    if (t < RSZ) sc[t] += u;
    __syncthreads();
  }
  if (t < RSZ) {
    int pos = cb + sc[t] - v;
    int node = (b << RB) + t;
    if (node < N) {
      off[node] = pos;
      dinv[node] = rsqrtf((float)v + 2.0f);  // degree + 2 self-loops
    }
    cur[t] = pos;
  }
  __syncthreads();
  for (int i = t; i < cnt_b; i += 512) {
    unsigned int en = src[i];
    int p = atomicAdd(&cur[en & (RSZ - 1)], 1);
    eidx[p] = (int)((en >> RB) * (unsigned)PROWB);   // byte offset of plane row
  }
}

// ---------- projection: g0 planes = bf16( dinv[n] * (x[n] @ W^T) ) ----------
// Register-blocked 2 nodes/thread; plane p holds classes [p*20, p*20+20) as
// 40 B rows at base g0 + p*N*PC ushorts.
__global__ __launch_bounds__(128) void k_xw_scale(
    const float* __restrict__ x, const float* __restrict__ W,
    const float* __restrict__ dinv, unsigned short* __restrict__ g0,
    int N, int NH) {
  __shared__ float4 Ws[NC * (DF / 4)];  // 20 KB
  for (int i = threadIdx.x; i < NC * (DF / 4); i += blockDim.x)
    Ws[i] = ((const float4*)W)[i];
  __syncthreads();
  int t = blockIdx.x * blockDim.x + threadIdx.x;
  if (t >= NH) return;
  int n0 = t;
  int n1 = t + NH;
  bool has1 = n1 < N;
  int n1c = has1 ? n1 : n0;
  float acc0[NC], acc1[NC];
#pragma unroll
  for (int c = 0; c < NC; ++c) { acc0[c] = 0.f; acc1[c] = 0.f; }
  const float4* xr0 = (const float4*)(x + (size_t)n0 * DF);
  const float4* xr1 = (const float4*)(x + (size_t)n1c * DF);
#pragma unroll 1
  for (int ch = 0; ch < 8; ++ch) {
    float4 a0 = xr0[ch * 4 + 0], a1 = xr0[ch * 4 + 1];
    float4 a2 = xr0[ch * 4 + 2], a3 = xr0[ch * 4 + 3];
    float4 b0 = xr1[ch * 4 + 0], b1 = xr1[ch * 4 + 1];
    float4 b2 = xr1[ch * 4 + 2], b3 = xr1[ch * 4 + 3];
#pragma unroll
    for (int c = 0; c < NC; ++c) {
      float4 w0 = Ws[c * (DF / 4) + ch * 4 + 0];
      float4 w1 = Ws[c * (DF / 4) + ch * 4 + 1];
      float4 w2 = Ws[c * (DF / 4) + ch * 4 + 2];
      float4 w3 = Ws[c * (DF / 4) + ch * 4 + 3];
      acc0[c] += (a0.x * w0.x + a0.y * w0.y + a0.z * w0.z + a0.w * w0.w) +
                 (a1.x * w1.x + a1.y * w1.y + a1.z * w1.z + a1.w * w1.w) +
                 (a2.x * w2.x + a2.y * w2.y + a2.z * w2.z + a2.w * w2.w) +
                 (a3.x * w3.x + a3.y * w3.y + a3.z * w3.z + a3.w * w3.w);
      acc1[c] += (b0.x * w0.x + b0.y * w0.y + b0.z * w0.z + b0.w * w0.w) +
                 (b1.x * w1.x + b1.y * w1.y + b1.z * w1.z + b1.w * w1.w) +
                 (b2.x * w2.x + b2.y * w2.y + b2.z * w2.z + b2.w * w2.w) +
                 (b3.x * w3.x + b3.y * w3.y + b3.z * w3.z + b3.w * w3.w);
    }
  }
  unsigned int pk[NC / 2];
  float di0 = dinv[n0];
#pragma unroll
  for (int c2 = 0; c2 < NC / 2; ++c2) {
    unsigned int lo = f2bf(di0 * acc0[c2 * 2 + 0]);
    unsigned int hi = f2bf(di0 * acc0[c2 * 2 + 1]);
    pk[c2] = lo | (hi << 16);
  }
  uint2* q0 = (uint2*)g0 + (size_t)n0 * 5;
  uint2* q1 = (uint2*)g0 + (size_t)N * 5 + (size_t)n0 * 5;
#pragma unroll
  for (int q = 0; q < 5; ++q) {
    q0[q] = make_uint2(pk[2 * q], pk[2 * q + 1]);
    q1[q] = make_uint2(pk[10 + 2 * q], pk[10 + 2 * q + 1]);
  }
  if (has1) {
    float di1 = dinv[n1];
#pragma unroll
    for (int c2 = 0; c2 < NC / 2; ++c2) {
      unsigned int lo = f2bf(di1 * acc1[c2 * 2 + 0]);
      unsigned int hi = f2bf(di1 * acc1[c2 * 2 + 1]);
      pk[c2] = lo | (hi << 16);
    }
    uint2* r0 = (uint2*)g0 + (size_t)n1 * 5;
    uint2* r1 = (uint2*)g0 + (size_t)N * 5 + (size_t)n1 * 5;
#pragma unroll
    for (int q = 0; q < 5; ++q) {
      r0[q] = make_uint2(pk[2 * q], pk[2 * q + 1]);
      r1[q] = make_uint2(pk[10 + 2 * q], pk[10 + 2 * q + 1]);
    }
  }
}

// ---------- hop: plane-split x 12-edges-per-gather ----------
// One wave = 2 nodes x 1 plane. 60 lanes = 12 edge-slots x 5 class-lanes;
// lane loads uint2 (4 classes, 8 B) -> one gather covers 12 edges' 40 B rows.
// Per node: 48-edge masked clamped shot (4 eidx loads + 4 gathers); both
// nodes interleaved = 8 gathers in flight. Tail (deg>48, ~0.3%) rolled.
// Block->plane via blockIdx%8: XCDs 0-3 plane 0, XCDs 4-7 plane 1 (FETCH
// reduction verified rounds 2-4). FINAL writes f32 logits (k_lsm finishes).
template<int FINAL>
__global__ __launch_bounds__(256) void k_hop(
    const int* __restrict__ off, const int* __restrict__ eidx,
    const float* __restrict__ dinv, const unsigned short* __restrict__ gin,
    unsigned short* __restrict__ gout, float* __restrict__ logits,
    const float* __restrict__ bias, int N, int NBH) {
  int bid = blockIdx.x;
  int slot8 = bid & 7;
  int half = slot8 >> 2;                       // plane id 0/1
  int nbi = ((bid >> 3) << 2) + (slot8 & 3);   // node-block index within plane
  if (nbi >= NBH) return;
  int lane = threadIdx.x & 63;
  int nA = nbi * 8 + ((threadIdx.x >> 6) << 1);  // 8 nodes/block, 2 per wave
  if (nA >= N) return;
  bool hasB = (nA + 1) < N;
  int nB = hasB ? nA + 1 : nA;
  int slot = lane / 5;                 // 0..11 edge slots; lanes 60-63 -> 12 (dead)
  int j = lane - slot * 5;             // uint2 index within 40 B row
  int j8 = j * 8;
  bool act = slot < 12;
  const char* plane = (const char*)gin + (size_t)half * ((size_t)N * PROWB);
  int sA = __builtin_amdgcn_readfirstlane(off[nA]);
  int eA = __builtin_amdgcn_readfirstlane(off[nA + 1]);
  int sB = eA;                          // CSR adjacency
  int eB = hasB ? __builtin_amdgcn_readfirstlane(off[nA + 2]) : eA;
  float diA = dinv[nA];
  float diB = dinv[nB];
  // self rows (double self-loop): slot 0 only
  float mself = (slot == 0) ? 2.f : 0.f;
  uint2 svA = *(const uint2*)(plane + (size_t)nA * PROWB + j8);
  uint2 svB = *(const uint2*)(plane + (size_t)nB * PROWB + j8);
  float A0 = mself * blo(svA.x), A1 = mself * bhi(svA.x);
  float A2 = mself * blo(svA.y), A3 = mself * bhi(svA.y);
  float B0 = mself * blo(svB.x), B1 = mself * bhi(svB.x);
  float B2 = mself * blo(svB.y), B3 = mself * bhi(svB.y);
  int lastA = (eA > sA) ? eA - 1 : 0;
  int lastB = (eB > sB) ? eB - 1 : 0;
  {  // 48-edge masked shot per node, both nodes interleaved: 8 gathers in flight
    int pa0 = sA + slot, pa1 = pa0 + 12, pa2 = pa0 + 24, pa3 = pa0 + 36;
    int pb0 = sB + slot, pb1 = pb0 + 12, pb2 = pb0 + 24, pb3 = pb0 + 36;
    int ra0 = __builtin_nontemporal_load(eidx + min(pa0, lastA));
    int ra1 = __builtin_nontemporal_load(eidx + min(pa1, lastA));
    int ra2 = __builtin_nontemporal_load(eidx + min(pa2, lastA));
    int ra3 = __builtin_nontemporal_load(eidx + min(pa3, lastA));
    int rb0 = __builtin_nontemporal_load(eidx + min(pb0, lastB));
    int rb1 = __builtin_nontemporal_load(eidx + min(pb1, lastB));
    int rb2 = __builtin_nontemporal_load(eidx + min(pb2, lastB));
    int rb3 = __builtin_nontemporal_load(eidx + min(pb3, lastB));
    uint2 va0 = *(const uint2*)(plane + (unsigned)(ra0 + j8));
    uint2 va1 = *(const uint2*)(plane + (unsigned)(ra1 + j8));
    uint2 va2 = *(const uint2*)(plane + (unsigned)(ra2 + j8));
    uint2 va3 = *(const uint2*)(plane + (unsigned)(ra3 + j8));
    uint2 vb0 = *(const uint2*)(plane + (unsigned)(rb0 + j8));
    uint2 vb1 = *(const uint2*)(plane + (unsigned)(rb1 + j8));
    uint2 vb2 = *(const uint2*)(plane + (unsigned)(rb2 + j8));
    uint2 vb3 = *(const uint2*)(plane + (unsigned)(rb3 + j8));
    float ma0 = (act && pa0 < eA) ? 1.f : 0.f;
    float ma1 = (act && pa1 < eA) ? 1.f : 0.f;
    float ma2 = (act && pa2 < eA) ? 1.f : 0.f;
    float ma3 = (act && pa3 < eA) ? 1.f : 0.f;
    float mb0 = (act && pb0 < eB) ? 1.f : 0.f;
    float mb1 = (act && pb1 < eB) ? 1.f : 0.f;
    float mb2 = (act && pb2 < eB) ? 1.f : 0.f;
    float mb3 = (act && pb3 < eB) ? 1.f : 0.f;
    A0 += ma0 * blo(va0.x); A1 += ma0 * bhi(va0.x); A2 += ma0 * blo(va0.y); A3 += ma0 * bhi(va0.y);
    A0 += ma1 * blo(va1.x); A1 += ma1 * bhi(va1.x); A2 += ma1 * blo(va1.y); A3 += ma1 * bhi(va1.y);
    A0 += ma2 * blo(va2.x); A1 += ma2 * bhi(va2.x); A2 += ma2 * blo(va2.y); A3 += ma2 * bhi(va2.y);
    A0 += ma3 * blo(va3.x); A1 += ma3 * bhi(va3.x); A2 += ma3 * blo(va3.y); A3 += ma3 * bhi(va3.y);
    B0 += mb0 * blo(vb0.x); B1 += mb0 * bhi(vb0.x); B2 += mb0 * blo(vb0.y); B3 += mb0 * bhi(vb0.y);
    B0 += mb1 * blo(vb1.x); B1 += mb1 * bhi(vb1.x); B2 += mb1 * blo(vb1.y); B3 += mb1 * bhi(vb1.y);
    B0 += mb2 * blo(vb2.x); B1 += mb2 * bhi(vb2.x); B2 += mb2 * blo(vb2.y); B3 += mb2 * bhi(vb2.y);
    B0 += mb3 * blo(vb3.x); B1 += mb3 * bhi(vb3.x); B2 += mb3 * blo(vb3.y); B3 += mb3 * bhi(vb3.y);
  }
  // rare cleanup (deg > 48): rolled 12-edge masked batches
  for (int i = sA + 48; i < eA; i += 12) {
    int p = i + slot;
    int r = __builtin_nontemporal_load(eidx + min(p, lastA));
    uint2 v = *(const uint2*)(plane + (unsigned)(r + j8));
    float m = (act && p < eA) ? 1.f : 0.f;
    A0 += m * blo(v.x); A1 += m * bhi(v.x); A2 += m * blo(v.y); A3 += m * bhi(v.y);
  }
  for (int i = sB + 48; i < eB; i += 12) {
    int p = i + slot;
    int r = __builtin_nontemporal_load(eidx + min(p, lastB));
    uint2 v = *(const uint2*)(plane + (unsigned)(r + j8));
    float m = (act && p < eB) ? 1.f : 0.f;
    B0 += m * blo(v.x); B1 += m * bhi(v.x); B2 += m * blo(v.y); B3 += m * bhi(v.y);
  }
  // reduce 12 slots (stride 5) onto slot 0; A/B chains interleave
  int l30 = (lane + 30) & 63, l15 = (lane + 15) & 63;
  int l5 = (lane + 5) & 63, l10 = (lane + 10) & 63;
  A0 += __shfl(A0, l30, 64); B0 += __shfl(B0, l30, 64);
  A1 += __shfl(A1, l30, 64); B1 += __shfl(B1, l30, 64);
  A2 += __shfl(A2, l30, 64); B2 += __shfl(B2, l30, 64);
  A3 += __shfl(A3, l30, 64); B3 += __shfl(B3, l30, 64);
  A0 += __shfl(A0, l15, 64); B0 += __shfl(B0, l15, 64);
  A1 += __shfl(A1, l15, 64); B1 += __shfl(B1, l15, 64);
  A2 += __shfl(A2, l15, 64); B2 += __shfl(B2, l15, 64);
  A3 += __shfl(A3, l15, 64); B3 += __shfl(B3, l15, 64);
  A0 = A0 + __shfl(A0, l5, 64) + __shfl(A0, l10, 64);
  B0 = B0 + __shfl(B0, l5, 64) + __shfl(B0, l10, 64);
  A1 = A1 + __shfl(A1, l5, 64) + __shfl(A1, l10, 64);
  B1 = B1 + __shfl(B1, l5, 64) + __shfl(B1, l10, 64);
  A2 = A2 + __shfl(A2, l5, 64) + __shfl(A2, l10, 64);
  B2 = B2 + __shfl(B2, l5, 64) + __shfl(B2, l10, 64);
  A3 = A3 + __shfl(A3, l5, 64) + __shfl(A3, l10, 64);
  B3 = B3 + __shfl(B3, l5, 64) + __shfl(B3, l10, 64);
  if (slot == 0) {                     // lanes 0..4 hold classes 4j..4j+3 of this plane
    if (FINAL) {
      float4 bb = *(const float4*)(bias + half * PC + 4 * j);
      f32x4 lgA = { diA * A0 + bb.x, diA * A1 + bb.y, diA * A2 + bb.z, diA * A3 + bb.w };
      __builtin_nontemporal_store(lgA,
          (f32x4*)(logits + (size_t)nA * NC + half * PC + 4 * j));
      if (hasB) {
        f32x4 lgB = { diB * B0 + bb.x, diB * B1 + bb.y, diB * B2 + bb.z, diB * B3 + bb.w };
        __builtin_nontemporal_store(lgB,
            (f32x4*)(logits + (size_t)nB * NC + half * PC + 4 * j));
      }
    } else {
      float scA = diA * diA;
      unsigned lo = (unsigned)f2bf(scA * A0) | ((unsigned)f2bf(scA * A1) << 16);
      unsigned hi = (unsigned)f2bf(scA * A2) | ((unsigned)f2bf(scA * A3) << 16);
      unsigned long long pk = (unsigned long long)lo | ((unsigned long long)hi << 32);
      __builtin_nontemporal_store(pk,
          (unsigned long long*)((char*)gout + (size_t)half * ((size_t)N * PROWB) +
                                (size_t)nA * PROWB + j8));
      if (hasB) {
        float scB = diB * diB;
        unsigned lo2 = (unsigned)f2bf(scB * B0) | ((unsigned)f2bf(scB * B1) << 16);
        unsigned hi2 = (unsigned)f2bf(scB * B2) | ((unsigned)f2bf(scB * B3) << 16);
        unsigned long long pk2 = (unsigned long long)lo2 | ((unsigned long long)hi2 << 32);
        __builtin_nontemporal_store(pk2,
            (unsigned long long*)((char*)gout + (size_t)half * ((size_t)N * PROWB) +
                                  (size_t)nB * PROWB + j8));
      }
    }
  }
}

// ---------- epilogue: log_softmax over f32 logits ----------
__global__ __launch_bounds__(256) void k_lsm(
    const float* __restrict__ logits, float* __restrict__ out, int N) {
  int wave = (int)((blockIdx.x * (size_t)blockDim.x + threadIdx.x) >> 6);
  int lane = threadIdx.x & 63;
  if (wave >= N) return;
  bool act = lane < NC;
  float v = act ? __builtin_nontemporal_load(logits + (size_t)wave * NC + lane) : -3.0e38f;
  float m = v;
#pragma unroll
  for (int o = 32; o > 0; o >>= 1) m = fmaxf(m, __shfl_xor(m, o, 64));
  float ex = act ? expf(v - m) : 0.f;
  float ssum = ex;
#pragma unroll
  for (int o = 32; o > 0; o >>= 1) ssum += __shfl_xor(ssum, o, 64);
  float lse = m + logf(ssum);
  if (act) __builtin_nontemporal_store(v - lse, out + (size_t)wave * NC + lane);
}

extern "C" void kernel_launch(void* const* d_in, const int* in_sizes, int n_in,
                              void* d_out, int out_size, void* d_ws, size_t ws_size,
                              hipStream_t stream) {
  const float* x = (const float*)d_in[0];
  const int* ei  = (const int*)d_in[1];   // [2][E] flat: rows then cols
  const float* W = (const float*)d_in[2];
  const float* b = (const float*)d_in[3];
  // d_in[4] is K; reference fixes K=2 — hardcoded.
  float* out = (float*)d_out;

  const int N = in_sizes[0] / DF;
  const int E = in_sizes[1] / 2;
  const int NB = (N + RSZ - 1) >> RB;
  const int* row  = ei;
  const int* colv = ei + E;

  char* basep = (char*)d_ws;
  auto alloc = [&](size_t bytes) {
    char* p = basep;
    basep += (bytes + 511) & ~(size_t)511;
    return p;
  };
  int*   cnt    = (int*)  alloc(((size_t)NB) * 4);
  unsigned int* slab = (unsigned int*)alloc((size_t)NB * CAP * 4);  // 19.2 MB
  int*   off    = (int*)  alloc(((size_t)N + 1) * 4);
  int*   eidx   = (int*)  alloc((size_t)E * 4);
  float* dinv   = (float*)alloc((size_t)N * 4);
  unsigned short* g0 = (unsigned short*)alloc((size_t)N * NC * 2);  // 8 MB, 2 planes
  unsigned short* g1 = (unsigned short*)alloc((size_t)N * NC * 2);
  // logits [N][NC] f32 aliases the slab (dead after k_binC; 19.2 >= 16 MB)
  float* logits = (float*)slab;

  const int gBin = (E + CHUNK - 1) / CHUNK;

  hipMemsetAsync(cnt, 0, (size_t)NB * 4, stream);
  k_binB<<<gBin, 512, 0, stream>>>(row, colv, cnt, slab, E, NB);
  k_binC<<<NB, 512, 0, stream>>>(slab, cnt, off, eidx, dinv, N, NB, E);

  const int NH = (N + 1) / 2;
  k_xw_scale<<<(NH + 127) / 128, 128, 0, stream>>>(x, W, dinv, g0, N, NH);

  // two hops, each split into two XCD-affine class-plane passes in one grid
  const int NBH = (N + 7) >> 3;         // 8 nodes per block (4 waves x 2 nodes)
  const int NBH4 = (NBH + 3) & ~3;
  const int gHop = 2 * NBH4;            // multiple of 8: clean XCD round-robin
  k_hop<0><<<gHop, 256, 0, stream>>>(off, eidx, dinv, g0, g1, nullptr, nullptr, N, NBH);
  k_hop<1><<<gHop, 256, 0, stream>>>(off, eidx, dinv, g1, nullptr, logits, b, N, NBH);

  const int gLsm = (int)(((size_t)N * 64 + 255) / 256);
  k_lsm<<<gLsm, 256, 0, stream>>>(logits, out, N);
}